// Round 5
// baseline (4055.138 us; speedup 1.0000x reference)
//
#include <hip/hip_runtime.h>

#define N_NODES 10000
#define N_EDGES 100000
#define IN_CH 64
#define EDGE_DIM 16
#define HID 128
#define HEADS 4
#define HC 512          // HEADS*HID
#define LAYERS 4
#define NUM_GRAPHS 256
#define NCAT 1152       // 512(xl) + 512(xr) + 128(res) packed cols
#define LDP 136         // padded LDS stride (bf16 elems)
#define EPB 16          // edges per block in logits kernel (8 per wave-pair)

typedef __bf16 bf16;
typedef __bf16 bf16x8 __attribute__((ext_vector_type(8)));
typedef __bf16 bf16x4 __attribute__((ext_vector_type(4)));
typedef float floatx4 __attribute__((ext_vector_type(4)));
typedef float f32x2 __attribute__((ext_vector_type(2)));

__device__ __forceinline__ float elu_f(float x) { return x > 0.f ? x : (__expf(x) - 1.f); }

// ---------------- weight prep: WT[l][n][k] bf16, coalesced via LDS transpose ----
// grid (9, LAYERS, 8), block 128. nt: 0-3=Wl, 4-7=Wr, 8=Wres. z = 16-row k-chunk.
__global__ __launch_bounds__(128) void k_prep_w(
    const float* __restrict__ Wl, const float* __restrict__ bl,
    const float* __restrict__ Wr, const float* __restrict__ br,
    const float* __restrict__ Wres, const float* __restrict__ bres,
    bf16* __restrict__ WT, float* __restrict__ bcat) {
    __shared__ float tile[16][129];
    int nt = blockIdx.x, i = blockIdx.y, z = blockIdx.z;
    int t = threadIdx.x;
    int n0 = nt * 128;
    const float* base = nullptr; const float* bsrc = nullptr; int ld = 0;
    if (nt < 4)       { base = Wl + (size_t)i * HID * HC + n0;            bsrc = bl + i * HC + n0;              ld = HC; }
    else if (nt < 8)  { base = Wr + (size_t)i * HID * HC + (n0 - 512);    bsrc = br + i * HC + (n0 - 512);      ld = HC; }
    else if (i > 0)   { base = Wres + (size_t)(i - 1) * HID * HID;        bsrc = bres + (size_t)(i - 1) * HID;  ld = HID; }
    if (base) {
#pragma unroll
        for (int r = 0; r < 16; r++) tile[r][t] = base[(size_t)(z * 16 + r) * ld + t];
    } else {
#pragma unroll
        for (int r = 0; r < 16; r++) tile[r][t] = 0.f;
    }
    __syncthreads();
    int n = n0 + t;
    if (z == 0) bcat[(size_t)i * NCAT + n] = base ? bsrc[t] : 0.f;
    bf16* dst = WT + ((size_t)i * NCAT + n) * HID + z * 16;
#pragma unroll
    for (int kc = 0; kc < 2; kc++) {
        bf16x8 v;
#pragma unroll
        for (int u = 0; u < 8; u++) v[u] = (bf16)tile[kc * 8 + u][t];
        *(bf16x8*)(dst + kc * 8) = v;
    }
}

// ---------------- h0 = elu(x @ Win + b_in) ----------------
__global__ __launch_bounds__(128) void k_init_h(const float* __restrict__ x,
                                                const float* __restrict__ Win,
                                                const float* __restrict__ b_in,
                                                bf16* __restrict__ h_bf) {
    __shared__ float xs[IN_CH];
    int n = blockIdx.x, t = threadIdx.x;
    if (t < IN_CH) xs[t] = x[(size_t)n * IN_CH + t];
    __syncthreads();
    float s = b_in[t];
#pragma unroll 8
    for (int k = 0; k < IN_CH; k++) s = fmaf(xs[k], Win[k * HID + t], s);
    h_bf[(size_t)n * HID + t] = (bf16)elu_f(s);
}

// ---------------- MFMA bf16 GEMM: C[M,NCAT] = A[M,128] @ WT^T + bias ------
__global__ __launch_bounds__(256, 2) void k_gemm_mfma(
    const bf16* __restrict__ A, const bf16* __restrict__ WT,
    const float* __restrict__ bcat, bf16* __restrict__ C, int M) {
    __shared__ __align__(16) unsigned short As[128 * LDP];
    __shared__ __align__(16) unsigned short Bs[128 * LDP];
    int t = threadIdx.x;
    int r0 = blockIdx.x * 128, c0 = blockIdx.y * 128;
#pragma unroll
    for (int i = 0; i < 8; i++) {
        int idx = t + i * 256;
        int row = idx >> 4;
        int ch = idx & 15;
        int r = r0 + row; if (r >= M) r = M - 1;
        uint4 va = *(const uint4*)(A + (size_t)r * HID + ch * 8);
        *(uint4*)&As[row * LDP + ch * 8] = va;
        uint4 vb = *(const uint4*)(WT + (size_t)(c0 + row) * HID + ch * 8);
        *(uint4*)&Bs[row * LDP + ch * 8] = vb;
    }
    __syncthreads();

    int wave = t >> 6, lane = t & 63;
    int wm = wave & 1, wn = wave >> 1;
    int quad = lane >> 4, lm = lane & 15;
    floatx4 zero = {0.f, 0.f, 0.f, 0.f};
    floatx4 acc[4][4];
#pragma unroll
    for (int mi = 0; mi < 4; mi++)
#pragma unroll
        for (int ni = 0; ni < 4; ni++) acc[mi][ni] = zero;

    const unsigned short* Ab = &As[(wm * 64 + lm) * LDP + quad * 8];
    const unsigned short* Bb = &Bs[(wn * 64 + lm) * LDP + quad * 8];
#pragma unroll
    for (int ks = 0; ks < 4; ks++) {
        bf16x8 af[4], bfr[4];
#pragma unroll
        for (int mi = 0; mi < 4; mi++) af[mi] = *(const bf16x8*)(Ab + mi * 16 * LDP + ks * 32);
#pragma unroll
        for (int ni = 0; ni < 4; ni++) bfr[ni] = *(const bf16x8*)(Bb + ni * 16 * LDP + ks * 32);
#pragma unroll
        for (int mi = 0; mi < 4; mi++)
#pragma unroll
            for (int ni = 0; ni < 4; ni++)
                acc[mi][ni] = __builtin_amdgcn_mfma_f32_16x16x32_bf16(af[mi], bfr[ni], acc[mi][ni], 0, 0, 0);
    }

#pragma unroll
    for (int ni = 0; ni < 4; ni++) {
        int col = c0 + wn * 64 + ni * 16 + lm;
        float bias = bcat[col];
#pragma unroll
        for (int mi = 0; mi < 4; mi++) {
#pragma unroll
            for (int r = 0; r < 4; r++) {
                int row = r0 + wm * 64 + mi * 16 + quad * 4 + r;
                if (row < M) C[(size_t)row * NCAT + col] = (bf16)(acc[mi][ni][r] + bias);
            }
        }
    }
}

// ---------------- CSR build (+ per-graph node counts folded in) ----------------
__global__ void k_degree(const int* __restrict__ ei, const int* __restrict__ batch,
                         int* __restrict__ deg, int* __restrict__ cnt) {
    int e = blockIdx.x * blockDim.x + threadIdx.x;
    if (e < N_EDGES) atomicAdd(&deg[ei[N_EDGES + e]], 1);
    if (e < N_NODES) atomicAdd(&cnt[batch[e]], 1);
}

// shfl-based scan
__global__ __launch_bounds__(1024) void k_scan(const int* __restrict__ deg,
                                               int* __restrict__ row_start,
                                               int* __restrict__ cursor) {
    __shared__ int wsum[16];
    __shared__ int carry_s;
    int t = threadIdx.x;
    int wave = t >> 6, lane = t & 63;
    if (t == 0) { carry_s = 0; row_start[0] = 0; }
    __syncthreads();
    for (int base = 0; base < N_NODES; base += 1024) {
        int i = base + t;
        int v = (i < N_NODES) ? deg[i] : 0;
        int incl = v;
#pragma unroll
        for (int off = 1; off < 64; off <<= 1) {
            int u = __shfl_up(incl, off, 64);
            if (lane >= off) incl += u;
        }
        if (lane == 63) wsum[wave] = incl;
        __syncthreads();
        if (wave == 0) {
            int ws = (lane < 16) ? wsum[lane] : 0;
#pragma unroll
            for (int off = 1; off < 16; off <<= 1) {
                int u = __shfl_up(ws, off, 64);
                if (lane >= off) ws += u;
            }
            if (lane < 16) wsum[lane] = ws;
        }
        __syncthreads();
        int carry = carry_s;
        int chunk_total = wsum[15];
        int total = carry + ((wave == 0) ? 0 : wsum[wave - 1]) + incl;
        if (i < N_NODES) { row_start[i + 1] = total; cursor[i] = total - v; }
        __syncthreads();
        if (t == 0) carry_s = carry + chunk_total;
    }
}

// scatter edges into CSR order; also permute edge_attr so logits reads are coalesced
__global__ void k_scatter(const int* __restrict__ ei, const float* __restrict__ edge_attr,
                          int* __restrict__ cursor,
                          int* __restrict__ ssrc, int* __restrict__ sdst,
                          float* __restrict__ ea_s) {
    int e = blockIdx.x * blockDim.x + threadIdx.x;
    if (e < N_EDGES) {
        int d = ei[N_EDGES + e];
        int pos = atomicAdd(&cursor[d], 1);
        ssrc[pos] = ei[e];
        sdst[pos] = d;
        const float4* s4 = (const float4*)(edge_attr + (size_t)e * EDGE_DIM);
        float4* d4 = (float4*)(ea_s + (size_t)pos * EDGE_DIM);
        d4[0] = s4[0]; d4[1] = s4[1]; d4[2] = s4[2]; d4[3] = s4[3];
    }
}

// ---------------- edge-parallel logits, strip of 16 edges per 256-thr block ----
// 2 wave-pairs; wave-pair wp handles 8 edges. K-outer loop: per k one We load
// feeds 8 edge accumulators (registers, non-rematerializable). edge_attr staged
// TRANSPOSED in LDS so the k-loop reads it as broadcast ds_read_b128.
__global__ __launch_bounds__(256, 4) void k_edge_logits(
    const bf16* __restrict__ xlr, const float* __restrict__ ea_s,
    const int* __restrict__ ssrc, const int* __restrict__ sdst,
    const float* __restrict__ We_l, const float* __restrict__ att_l,
    float* __restrict__ slogit) {
    int j0 = blockIdx.x * EPB;
    int t = threadIdx.x;
    int wp = t >> 7;            // wave-pair 0/1
    int tp = t & 127;
    int c0 = (tp >> 6) * 256 + (tp & 63) * 4;
    int head = c0 >> 7;

    __shared__ float east[16][16];     // [k][jj] transposed edge_attr strip
    __shared__ int s_sh[EPB], d_sh[EPB];
    if (t < 64) {
        int jj = t & 15, q = t >> 4;   // q = k-quad
        float4 v = *(const float4*)(ea_s + (size_t)(j0 + jj) * EDGE_DIM + q * 4);
        east[q * 4 + 0][jj] = v.x;
        east[q * 4 + 1][jj] = v.y;
        east[q * 4 + 2][jj] = v.z;
        east[q * 4 + 3][jj] = v.w;
    } else if (t < 80) {
        s_sh[t - 64] = ssrc[j0 + t - 64];
    } else if (t < 96) {
        d_sh[t - 80] = sdst[j0 + t - 80];
    }
    float4 att4 = *(const float4*)(att_l + head * HID + (c0 & 127));
    __syncthreads();

    int b = wp * 8;
    // issue all 16 gathers up front (independent, stay in flight)
    bf16x4 vl[8], vr[8];
#pragma unroll
    for (int e = 0; e < 8; e++) {
        int s = s_sh[b + e], d = d_sh[b + e];
        vl[e] = *(const bf16x4*)(xlr + (size_t)s * NCAT + c0);
        vr[e] = *(const bf16x4*)(xlr + (size_t)d * NCAT + 512 + c0);
    }
    // k-outer accumulation: acc is forced to live in registers
    f32x2 a0[8], a1[8];
#pragma unroll
    for (int e = 0; e < 8; e++) { a0[e] = (f32x2)0.f; a1[e] = (f32x2)0.f; }
#pragma unroll
    for (int k = 0; k < 16; k++) {
        float4 w = *(const float4*)(We_l + k * HC + c0);
        f32x2 w0 = {w.x, w.y}, w1 = {w.z, w.w};
        float4 eA = *(const float4*)&east[k][b];       // edges b..b+3 (broadcast)
        float4 eB = *(const float4*)&east[k][b + 4];   // edges b+4..b+7
        a0[0] += w0 * eA.x; a1[0] += w1 * eA.x;
        a0[1] += w0 * eA.y; a1[1] += w1 * eA.y;
        a0[2] += w0 * eA.z; a1[2] += w1 * eA.z;
        a0[3] += w0 * eA.w; a1[3] += w1 * eA.w;
        a0[4] += w0 * eB.x; a1[4] += w1 * eB.x;
        a0[5] += w0 * eB.y; a1[5] += w1 * eB.y;
        a0[6] += w0 * eB.z; a1[6] += w1 * eB.z;
        a0[7] += w0 * eB.w; a1[7] += w1 * eB.w;
    }
#pragma unroll
    for (int e = 0; e < 8; e++) {
        float m0 = (float)vl[e][0] + (float)vr[e][0] + a0[e].x;
        float m1 = (float)vl[e][1] + (float)vr[e][1] + a0[e].y;
        float m2 = (float)vl[e][2] + (float)vr[e][2] + a1[e].x;
        float m3 = (float)vl[e][3] + (float)vr[e][3] + a1[e].y;
        m0 = m0 > 0.f ? m0 : 0.2f * m0;
        m1 = m1 > 0.f ? m1 : 0.2f * m1;
        m2 = m2 > 0.f ? m2 : 0.2f * m2;
        m3 = m3 > 0.f ? m3 : 0.2f * m3;
        float partial = m0 * att4.x + m1 * att4.y + m2 * att4.z + m3 * att4.w;
#pragma unroll
        for (int off = 1; off < 32; off <<= 1) partial += __shfl_xor(partial, off, 64);
        if ((t & 31) == 0) slogit[(size_t)(j0 + b + e) * 4 + head] = partial;
    }
}

// ---------------- node-parallel softmax + aggregate + head-mean + LN + ELU ----
__global__ __launch_bounds__(128) void k_edge_agg(
    const bf16* __restrict__ xlr,
    const int* __restrict__ row_start, const int* __restrict__ ssrc,
    const float* __restrict__ slogit,
    const float* __restrict__ bgat_l, const float* __restrict__ gamma_l,
    const float* __restrict__ beta_l,
    int has_res,
    const int* __restrict__ batch, float* __restrict__ hsum, int do_pool,
    bf16* __restrict__ hbf_out) {
    int n = blockIdx.x;
    int t = threadIdx.x;
    int wave = t >> 6;
    int lane = t & 63;
    int c0 = wave * 256 + lane * 4;
    int head = c0 >> 7;

    int e0 = row_start[n], e1 = row_start[n + 1];

    float l0 = 0.f, l1 = 0.f;
    float4 a0 = {0.f, 0.f, 0.f, 0.f}, a1 = {0.f, 0.f, 0.f, 0.f};
    int j = e0;
    for (; j + 1 < e1; j += 2) {
        int s0 = ssrc[j], s1 = ssrc[j + 1];
        float p0 = __expf(slogit[(size_t)j * 4 + head]);
        float p1 = __expf(slogit[(size_t)(j + 1) * 4 + head]);
        bf16x4 v0 = *(const bf16x4*)(xlr + (size_t)s0 * NCAT + c0);
        bf16x4 v1 = *(const bf16x4*)(xlr + (size_t)s1 * NCAT + c0);
        l0 += p0; l1 += p1;
        a0.x = fmaf(p0, (float)v0[0], a0.x); a0.y = fmaf(p0, (float)v0[1], a0.y);
        a0.z = fmaf(p0, (float)v0[2], a0.z); a0.w = fmaf(p0, (float)v0[3], a0.w);
        a1.x = fmaf(p1, (float)v1[0], a1.x); a1.y = fmaf(p1, (float)v1[1], a1.y);
        a1.z = fmaf(p1, (float)v1[2], a1.z); a1.w = fmaf(p1, (float)v1[3], a1.w);
    }
    if (j < e1) {
        int s0 = ssrc[j];
        float p0 = __expf(slogit[(size_t)j * 4 + head]);
        bf16x4 v0 = *(const bf16x4*)(xlr + (size_t)s0 * NCAT + c0);
        l0 += p0;
        a0.x = fmaf(p0, (float)v0[0], a0.x); a0.y = fmaf(p0, (float)v0[1], a0.y);
        a0.z = fmaf(p0, (float)v0[2], a0.z); a0.w = fmaf(p0, (float)v0[3], a0.w);
    }
    float inv = 1.f / (l0 + l1 + 1e-16f);

    __shared__ float sout[HC];
    __shared__ float red[4];
    sout[c0 + 0] = (a0.x + a1.x) * inv;
    sout[c0 + 1] = (a0.y + a1.y) * inv;
    sout[c0 + 2] = (a0.z + a1.z) * inv;
    sout[c0 + 3] = (a0.w + a1.w) * inv;
    __syncthreads();

    int c = t;
    float v = 0.25f * (sout[c] + sout[c + 128] + sout[c + 256] + sout[c + 384]) + bgat_l[c];
    float s1 = v, s2 = v * v;
#pragma unroll
    for (int off = 1; off < 64; off <<= 1) {
        s1 += __shfl_xor(s1, off, 64);
        s2 += __shfl_xor(s2, off, 64);
    }
    if (lane == 0) { red[wave * 2] = s1; red[wave * 2 + 1] = s2; }
    __syncthreads();
    s1 = red[0] + red[2];
    s2 = red[1] + red[3];
    float mu = s1 * (1.f / HID);
    float var = s2 * (1.f / HID) - mu * mu;
    float rstd = rsqrtf(var + 1e-5f);
    float y = fmaf(gamma_l[c] * (v - mu), rstd, beta_l[c]);
    y = elu_f(y);
    if (has_res) y += (float)xlr[(size_t)n * NCAT + 1024 + c];
    if (do_pool) atomicAdd(&hsum[(size_t)batch[n] * HID + c], y);
    else hbf_out[(size_t)n * HID + c] = (bf16)y;
}

// ---------------- MLP head ----------------
__global__ __launch_bounds__(128) void k_mlp(const float* __restrict__ hsum,
                                             const int* __restrict__ cnt,
                                             const float* __restrict__ W1, const float* __restrict__ b1,
                                             const float* __restrict__ W2, const float* __restrict__ b2,
                                             const float* __restrict__ W3, const float* __restrict__ b3,
                                             float* __restrict__ out) {
    int g = blockIdx.x, t = threadIdx.x;
    __shared__ float hg[HID], z1[HID], z2[64];
    float invc = 1.f / fmaxf((float)cnt[g], 1.f);
    hg[t] = hsum[(size_t)g * HID + t] * invc;
    __syncthreads();
    float s = b1[t];
#pragma unroll 8
    for (int k = 0; k < HID; k++) s = fmaf(hg[k], W1[k * HID + t], s);
    z1[t] = fmaxf(s, 0.f);
    __syncthreads();
    if (t < 64) {
        float s2 = b2[t];
#pragma unroll 8
        for (int k = 0; k < HID; k++) s2 = fmaf(z1[k], W2[k * 64 + t], s2);
        z2[t] = fmaxf(s2, 0.f);
    }
    __syncthreads();
    if (t < 64) {
        float s3 = z2[t] * W3[t];
#pragma unroll
        for (int off = 1; off < 64; off <<= 1) s3 += __shfl_xor(s3, off, 64);
        if (t == 0) out[g] = s3 + b3[0];
    }
}

// ---------------- host launcher ----------------
extern "C" void kernel_launch(void* const* d_in, const int* in_sizes, int n_in,
                              void* d_out, int out_size, void* d_ws, size_t ws_size,
                              hipStream_t stream) {
    const float* x         = (const float*)d_in[0];
    const int*   ei        = (const int*)  d_in[1];
    const float* edge_attr = (const float*)d_in[2];
    const int*   batch     = (const int*)  d_in[3];
    const float* Win       = (const float*)d_in[4];
    const float* b_in      = (const float*)d_in[5];
    const float* Wl        = (const float*)d_in[6];
    const float* bl        = (const float*)d_in[7];
    const float* Wr        = (const float*)d_in[8];
    const float* br        = (const float*)d_in[9];
    const float* We        = (const float*)d_in[10];
    const float* att       = (const float*)d_in[11];
    const float* b_gat     = (const float*)d_in[12];
    const float* gamma     = (const float*)d_in[13];
    const float* beta      = (const float*)d_in[14];
    const float* Wres      = (const float*)d_in[15];
    const float* bres      = (const float*)d_in[16];
    const float* W1        = (const float*)d_in[17];
    const float* b1        = (const float*)d_in[18];
    const float* W2        = (const float*)d_in[19];
    const float* b2        = (const float*)d_in[20];
    const float* W3        = (const float*)d_in[21];
    const float* b3        = (const float*)d_in[22];
    float* out = (float*)d_out;

    char* ws = (char*)d_ws;
    size_t off = 0;
    auto alloc = [&](size_t bytes) -> void* {
        void* p = ws + off;
        off = (off + bytes + 255) & ~(size_t)255;
        return p;
    };
    bf16*  h_bf    = (bf16*) alloc((size_t)N_NODES * HID * 2);
    bf16*  xlr     = (bf16*) alloc((size_t)N_NODES * NCAT * 2);
    bf16*  WT      = (bf16*) alloc((size_t)LAYERS * NCAT * HID * 2);
    float* bcat    = (float*)alloc((size_t)LAYERS * NCAT * 4);
    float* slogit  = (float*)alloc((size_t)N_EDGES * 4 * 4);
    float* ea_s    = (float*)alloc((size_t)N_EDGES * EDGE_DIM * 4);
    // contiguous zero region: [hsum | cnt | deg]
    char*  zbase   = ws + off;
    float* hsum    = (float*)alloc((size_t)NUM_GRAPHS * HID * 4);
    int*   cnt     = (int*)  alloc((size_t)NUM_GRAPHS * 4);
    int*   deg     = (int*)  alloc((size_t)N_NODES * 4);
    size_t zlen    = (size_t)((ws + off) - zbase);
    int*   rowst   = (int*)  alloc((size_t)(N_NODES + 1) * 4);
    int*   cursor  = (int*)  alloc((size_t)N_NODES * 4);
    int*   ssrc    = (int*)  alloc((size_t)N_EDGES * 4);
    int*   sdst    = (int*)  alloc((size_t)N_EDGES * 4);
    (void)ws_size; // requires ~37 MB

    hipMemsetAsync(zbase, 0, zlen, stream);

    k_prep_w<<<dim3(9, LAYERS, 8), 128, 0, stream>>>(Wl, bl, Wr, br, Wres, bres, WT, bcat);
    k_degree<<<(N_EDGES + 255) / 256, 256, 0, stream>>>(ei, batch, deg, cnt);
    k_scan<<<1, 1024, 0, stream>>>(deg, rowst, cursor);
    k_scatter<<<(N_EDGES + 255) / 256, 256, 0, stream>>>(ei, edge_attr, cursor, ssrc, sdst, ea_s);
    k_init_h<<<N_NODES, 128, 0, stream>>>(x, Win, b_in, h_bf);

    const int MG = (N_NODES + 127) / 128;  // 79
    for (int i = 0; i < LAYERS; i++) {
        int ntiles = (i > 0) ? (NCAT / 128) : (1024 / 128);
        k_gemm_mfma<<<dim3(MG, ntiles), 256, 0, stream>>>(
            h_bf, WT + (size_t)i * NCAT * HID, bcat + (size_t)i * NCAT, xlr, N_NODES);
        k_edge_logits<<<N_EDGES / EPB, 256, 0, stream>>>(
            xlr, ea_s, ssrc, sdst,
            We + (size_t)i * EDGE_DIM * HC, att + (size_t)i * HEADS * HID, slogit);
        k_edge_agg<<<N_NODES, 128, 0, stream>>>(
            xlr, rowst, ssrc, slogit,
            b_gat + (size_t)i * HID, gamma + (size_t)i * HID, beta + (size_t)i * HID,
            (i > 0) ? 1 : 0,
            batch, hsum, (i == LAYERS - 1) ? 1 : 0, h_bf);
    }

    k_mlp<<<NUM_GRAPHS, 128, 0, stream>>>(hsum, cnt, W1, b1, W2, b2, W3, b3, out);
}

// Round 6
// 638.624 us; speedup vs baseline: 6.3498x; 6.3498x over previous
//
#include <hip/hip_runtime.h>

#define N_NODES 10000
#define N_EDGES 100000
#define IN_CH 64
#define EDGE_DIM 16
#define HID 128
#define HEADS 4
#define HC 512          // HEADS*HID
#define LAYERS 4
#define NUM_GRAPHS 256
#define NCAT 1152       // 512(xl) + 512(xr) + 128(res) packed cols
#define LDP 136         // padded LDS stride (bf16 elems)
#define EPB 16          // edges per block in logits kernel (8 per wave-pair)

typedef __bf16 bf16;
typedef __bf16 bf16x8 __attribute__((ext_vector_type(8)));
typedef __bf16 bf16x4 __attribute__((ext_vector_type(4)));
typedef float floatx4 __attribute__((ext_vector_type(4)));
typedef float f32x2 __attribute__((ext_vector_type(2)));

__device__ __forceinline__ float elu_f(float x) { return x > 0.f ? x : (__expf(x) - 1.f); }

// ---------------- weight prep: WT[l][n][k] bf16, coalesced via LDS transpose ----
// grid (9, LAYERS, 8), block 128. nt: 0-3=Wl, 4-7=Wr, 8=Wres. z = 16-row k-chunk.
__global__ __launch_bounds__(128) void k_prep_w(
    const float* __restrict__ Wl, const float* __restrict__ bl,
    const float* __restrict__ Wr, const float* __restrict__ br,
    const float* __restrict__ Wres, const float* __restrict__ bres,
    bf16* __restrict__ WT, float* __restrict__ bcat) {
    __shared__ float tile[16][129];
    int nt = blockIdx.x, i = blockIdx.y, z = blockIdx.z;
    int t = threadIdx.x;
    int n0 = nt * 128;
    const float* base = nullptr; const float* bsrc = nullptr; int ld = 0;
    if (nt < 4)       { base = Wl + (size_t)i * HID * HC + n0;            bsrc = bl + i * HC + n0;              ld = HC; }
    else if (nt < 8)  { base = Wr + (size_t)i * HID * HC + (n0 - 512);    bsrc = br + i * HC + (n0 - 512);      ld = HC; }
    else if (i > 0)   { base = Wres + (size_t)(i - 1) * HID * HID;        bsrc = bres + (size_t)(i - 1) * HID;  ld = HID; }
    if (base) {
#pragma unroll
        for (int r = 0; r < 16; r++) tile[r][t] = base[(size_t)(z * 16 + r) * ld + t];
    } else {
#pragma unroll
        for (int r = 0; r < 16; r++) tile[r][t] = 0.f;
    }
    __syncthreads();
    int n = n0 + t;
    if (z == 0) bcat[(size_t)i * NCAT + n] = base ? bsrc[t] : 0.f;
    bf16* dst = WT + ((size_t)i * NCAT + n) * HID + z * 16;
#pragma unroll
    for (int kc = 0; kc < 2; kc++) {
        bf16x8 v;
#pragma unroll
        for (int u = 0; u < 8; u++) v[u] = (bf16)tile[kc * 8 + u][t];
        *(bf16x8*)(dst + kc * 8) = v;
    }
}

// ---------------- h0 = elu(x @ Win + b_in) ----------------
__global__ __launch_bounds__(128) void k_init_h(const float* __restrict__ x,
                                                const float* __restrict__ Win,
                                                const float* __restrict__ b_in,
                                                bf16* __restrict__ h_bf) {
    __shared__ float xs[IN_CH];
    int n = blockIdx.x, t = threadIdx.x;
    if (t < IN_CH) xs[t] = x[(size_t)n * IN_CH + t];
    __syncthreads();
    float s = b_in[t];
#pragma unroll 8
    for (int k = 0; k < IN_CH; k++) s = fmaf(xs[k], Win[k * HID + t], s);
    h_bf[(size_t)n * HID + t] = (bf16)elu_f(s);
}

// ---------------- MFMA bf16 GEMM: C[M,NCAT] = A[M,128] @ WT^T + bias ------
__global__ __launch_bounds__(256, 2) void k_gemm_mfma(
    const bf16* __restrict__ A, const bf16* __restrict__ WT,
    const float* __restrict__ bcat, bf16* __restrict__ C, int M) {
    __shared__ __align__(16) unsigned short As[128 * LDP];
    __shared__ __align__(16) unsigned short Bs[128 * LDP];
    int t = threadIdx.x;
    int r0 = blockIdx.x * 128, c0 = blockIdx.y * 128;
#pragma unroll
    for (int i = 0; i < 8; i++) {
        int idx = t + i * 256;
        int row = idx >> 4;
        int ch = idx & 15;
        int r = r0 + row; if (r >= M) r = M - 1;
        uint4 va = *(const uint4*)(A + (size_t)r * HID + ch * 8);
        *(uint4*)&As[row * LDP + ch * 8] = va;
        uint4 vb = *(const uint4*)(WT + (size_t)(c0 + row) * HID + ch * 8);
        *(uint4*)&Bs[row * LDP + ch * 8] = vb;
    }
    __syncthreads();

    int wave = t >> 6, lane = t & 63;
    int wm = wave & 1, wn = wave >> 1;
    int quad = lane >> 4, lm = lane & 15;
    floatx4 zero = {0.f, 0.f, 0.f, 0.f};
    floatx4 acc[4][4];
#pragma unroll
    for (int mi = 0; mi < 4; mi++)
#pragma unroll
        for (int ni = 0; ni < 4; ni++) acc[mi][ni] = zero;

    const unsigned short* Ab = &As[(wm * 64 + lm) * LDP + quad * 8];
    const unsigned short* Bb = &Bs[(wn * 64 + lm) * LDP + quad * 8];
#pragma unroll
    for (int ks = 0; ks < 4; ks++) {
        bf16x8 af[4], bfr[4];
#pragma unroll
        for (int mi = 0; mi < 4; mi++) af[mi] = *(const bf16x8*)(Ab + mi * 16 * LDP + ks * 32);
#pragma unroll
        for (int ni = 0; ni < 4; ni++) bfr[ni] = *(const bf16x8*)(Bb + ni * 16 * LDP + ks * 32);
#pragma unroll
        for (int mi = 0; mi < 4; mi++)
#pragma unroll
            for (int ni = 0; ni < 4; ni++)
                acc[mi][ni] = __builtin_amdgcn_mfma_f32_16x16x32_bf16(af[mi], bfr[ni], acc[mi][ni], 0, 0, 0);
    }

#pragma unroll
    for (int ni = 0; ni < 4; ni++) {
        int col = c0 + wn * 64 + ni * 16 + lm;
        float bias = bcat[col];
#pragma unroll
        for (int mi = 0; mi < 4; mi++) {
#pragma unroll
            for (int r = 0; r < 4; r++) {
                int row = r0 + wm * 64 + mi * 16 + quad * 4 + r;
                if (row < M) C[(size_t)row * NCAT + col] = (bf16)(acc[mi][ni][r] + bias);
            }
        }
    }
}

// ---------------- CSR build (+ per-graph node counts folded in) ----------------
__global__ void k_degree(const int* __restrict__ ei, const int* __restrict__ batch,
                         int* __restrict__ deg, int* __restrict__ cnt) {
    int e = blockIdx.x * blockDim.x + threadIdx.x;
    if (e < N_EDGES) atomicAdd(&deg[ei[N_EDGES + e]], 1);
    if (e < N_NODES) atomicAdd(&cnt[batch[e]], 1);
}

// shfl-based scan
__global__ __launch_bounds__(1024) void k_scan(const int* __restrict__ deg,
                                               int* __restrict__ row_start,
                                               int* __restrict__ cursor) {
    __shared__ int wsum[16];
    __shared__ int carry_s;
    int t = threadIdx.x;
    int wave = t >> 6, lane = t & 63;
    if (t == 0) { carry_s = 0; row_start[0] = 0; }
    __syncthreads();
    for (int base = 0; base < N_NODES; base += 1024) {
        int i = base + t;
        int v = (i < N_NODES) ? deg[i] : 0;
        int incl = v;
#pragma unroll
        for (int off = 1; off < 64; off <<= 1) {
            int u = __shfl_up(incl, off, 64);
            if (lane >= off) incl += u;
        }
        if (lane == 63) wsum[wave] = incl;
        __syncthreads();
        if (wave == 0) {
            int ws = (lane < 16) ? wsum[lane] : 0;
#pragma unroll
            for (int off = 1; off < 16; off <<= 1) {
                int u = __shfl_up(ws, off, 64);
                if (lane >= off) ws += u;
            }
            if (lane < 16) wsum[lane] = ws;
        }
        __syncthreads();
        int carry = carry_s;
        int chunk_total = wsum[15];
        int total = carry + ((wave == 0) ? 0 : wsum[wave - 1]) + incl;
        if (i < N_NODES) { row_start[i + 1] = total; cursor[i] = total - v; }
        __syncthreads();
        if (t == 0) carry_s = carry + chunk_total;
    }
}

// scatter edges into CSR order; also permute edge_attr so logits reads are coalesced
__global__ void k_scatter(const int* __restrict__ ei, const float* __restrict__ edge_attr,
                          int* __restrict__ cursor,
                          int* __restrict__ ssrc, int* __restrict__ sdst,
                          float* __restrict__ ea_s) {
    int e = blockIdx.x * blockDim.x + threadIdx.x;
    if (e < N_EDGES) {
        int d = ei[N_EDGES + e];
        int pos = atomicAdd(&cursor[d], 1);
        ssrc[pos] = ei[e];
        sdst[pos] = d;
        const float4* s4 = (const float4*)(edge_attr + (size_t)e * EDGE_DIM);
        float4* d4 = (float4*)(ea_s + (size_t)pos * EDGE_DIM);
        d4[0] = s4[0]; d4[1] = s4[1]; d4[2] = s4[2]; d4[3] = s4[3];
    }
}

// ---------------- edge-parallel logits, strip of 16 edges per 256-thr block ----
// k-outer: per k one We float4 (VMEM, L2-hot, amortized over 8 edges) feeds 8
// edge accumulators (32 VGPRs). xl/xr gathers deferred to epilogue (not live
// across the k-loop) -> ~65 VGPR live, no spill. No launch_bounds VGPR cap.
__global__ __launch_bounds__(256) void k_edge_logits(
    const bf16* __restrict__ xlr, const float* __restrict__ ea_s,
    const int* __restrict__ ssrc, const int* __restrict__ sdst,
    const float* __restrict__ We_l, const float* __restrict__ att_l,
    float* __restrict__ slogit) {
    int j0 = blockIdx.x * EPB;
    int t = threadIdx.x;
    int wp = t >> 7;            // wave-pair 0/1
    int tp = t & 127;
    int c0 = (tp >> 6) * 256 + (tp & 63) * 4;
    int head = c0 >> 7;

    __shared__ float east[16][16];     // [k][jj] transposed edge_attr strip
    __shared__ int s_sh[EPB], d_sh[EPB];
    if (t < 64) {
        int jj = t & 15, q = t >> 4;   // q = k-quad
        float4 v = *(const float4*)(ea_s + (size_t)(j0 + jj) * EDGE_DIM + q * 4);
        east[q * 4 + 0][jj] = v.x;
        east[q * 4 + 1][jj] = v.y;
        east[q * 4 + 2][jj] = v.z;
        east[q * 4 + 3][jj] = v.w;
    } else if (t < 80) {
        s_sh[t - 64] = ssrc[j0 + t - 64];
    } else if (t < 96) {
        d_sh[t - 80] = sdst[j0 + t - 80];
    }
    float4 att4 = *(const float4*)(att_l + head * HID + (c0 & 127));
    __syncthreads();

    int b = wp * 8;
    // k-outer accumulation: 8 edge accumulators live in registers
    f32x2 a0[8], a1[8];
#pragma unroll
    for (int e = 0; e < 8; e++) { a0[e] = (f32x2)0.f; a1[e] = (f32x2)0.f; }
#pragma unroll
    for (int k = 0; k < 16; k++) {
        float4 w = *(const float4*)(We_l + k * HC + c0);
        f32x2 w0 = {w.x, w.y}, w1 = {w.z, w.w};
        float4 eA = *(const float4*)&east[k][b];       // edges b..b+3 (broadcast)
        float4 eB = *(const float4*)&east[k][b + 4];   // edges b+4..b+7
        a0[0] += w0 * eA.x; a1[0] += w1 * eA.x;
        a0[1] += w0 * eA.y; a1[1] += w1 * eA.y;
        a0[2] += w0 * eA.z; a1[2] += w1 * eA.z;
        a0[3] += w0 * eA.w; a1[3] += w1 * eA.w;
        a0[4] += w0 * eB.x; a1[4] += w1 * eB.x;
        a0[5] += w0 * eB.y; a1[5] += w1 * eB.y;
        a0[6] += w0 * eB.z; a1[6] += w1 * eB.z;
        a0[7] += w0 * eB.w; a1[7] += w1 * eB.w;
    }
    // epilogue: per-edge gathers (consumed immediately, not live across k-loop)
#pragma unroll
    for (int e = 0; e < 8; e++) {
        int s = s_sh[b + e], d = d_sh[b + e];
        bf16x4 vl = *(const bf16x4*)(xlr + (size_t)s * NCAT + c0);
        bf16x4 vr = *(const bf16x4*)(xlr + (size_t)d * NCAT + 512 + c0);
        float m0 = (float)vl[0] + (float)vr[0] + a0[e].x;
        float m1 = (float)vl[1] + (float)vr[1] + a0[e].y;
        float m2 = (float)vl[2] + (float)vr[2] + a1[e].x;
        float m3 = (float)vl[3] + (float)vr[3] + a1[e].y;
        m0 = m0 > 0.f ? m0 : 0.2f * m0;
        m1 = m1 > 0.f ? m1 : 0.2f * m1;
        m2 = m2 > 0.f ? m2 : 0.2f * m2;
        m3 = m3 > 0.f ? m3 : 0.2f * m3;
        float partial = m0 * att4.x + m1 * att4.y + m2 * att4.z + m3 * att4.w;
#pragma unroll
        for (int off = 1; off < 32; off <<= 1) partial += __shfl_xor(partial, off, 64);
        if ((t & 31) == 0) slogit[(size_t)(j0 + b + e) * 4 + head] = partial;
    }
}

// ---------------- node-parallel softmax + aggregate + head-mean + LN + ELU ----
__global__ __launch_bounds__(128) void k_edge_agg(
    const bf16* __restrict__ xlr,
    const int* __restrict__ row_start, const int* __restrict__ ssrc,
    const float* __restrict__ slogit,
    const float* __restrict__ bgat_l, const float* __restrict__ gamma_l,
    const float* __restrict__ beta_l,
    int has_res,
    const int* __restrict__ batch, float* __restrict__ hsum, int do_pool,
    bf16* __restrict__ hbf_out) {
    int n = blockIdx.x;
    int t = threadIdx.x;
    int wave = t >> 6;
    int lane = t & 63;
    int c0 = wave * 256 + lane * 4;
    int head = c0 >> 7;

    int e0 = row_start[n], e1 = row_start[n + 1];

    float l0 = 0.f, l1 = 0.f;
    float4 a0 = {0.f, 0.f, 0.f, 0.f}, a1 = {0.f, 0.f, 0.f, 0.f};
    int j = e0;
    for (; j + 1 < e1; j += 2) {
        int s0 = ssrc[j], s1 = ssrc[j + 1];
        float p0 = __expf(slogit[(size_t)j * 4 + head]);
        float p1 = __expf(slogit[(size_t)(j + 1) * 4 + head]);
        bf16x4 v0 = *(const bf16x4*)(xlr + (size_t)s0 * NCAT + c0);
        bf16x4 v1 = *(const bf16x4*)(xlr + (size_t)s1 * NCAT + c0);
        l0 += p0; l1 += p1;
        a0.x = fmaf(p0, (float)v0[0], a0.x); a0.y = fmaf(p0, (float)v0[1], a0.y);
        a0.z = fmaf(p0, (float)v0[2], a0.z); a0.w = fmaf(p0, (float)v0[3], a0.w);
        a1.x = fmaf(p1, (float)v1[0], a1.x); a1.y = fmaf(p1, (float)v1[1], a1.y);
        a1.z = fmaf(p1, (float)v1[2], a1.z); a1.w = fmaf(p1, (float)v1[3], a1.w);
    }
    if (j < e1) {
        int s0 = ssrc[j];
        float p0 = __expf(slogit[(size_t)j * 4 + head]);
        bf16x4 v0 = *(const bf16x4*)(xlr + (size_t)s0 * NCAT + c0);
        l0 += p0;
        a0.x = fmaf(p0, (float)v0[0], a0.x); a0.y = fmaf(p0, (float)v0[1], a0.y);
        a0.z = fmaf(p0, (float)v0[2], a0.z); a0.w = fmaf(p0, (float)v0[3], a0.w);
    }
    float inv = 1.f / (l0 + l1 + 1e-16f);

    __shared__ float sout[HC];
    __shared__ float red[4];
    sout[c0 + 0] = (a0.x + a1.x) * inv;
    sout[c0 + 1] = (a0.y + a1.y) * inv;
    sout[c0 + 2] = (a0.z + a1.z) * inv;
    sout[c0 + 3] = (a0.w + a1.w) * inv;
    __syncthreads();

    int c = t;
    float v = 0.25f * (sout[c] + sout[c + 128] + sout[c + 256] + sout[c + 384]) + bgat_l[c];
    float s1 = v, s2 = v * v;
#pragma unroll
    for (int off = 1; off < 64; off <<= 1) {
        s1 += __shfl_xor(s1, off, 64);
        s2 += __shfl_xor(s2, off, 64);
    }
    if (lane == 0) { red[wave * 2] = s1; red[wave * 2 + 1] = s2; }
    __syncthreads();
    s1 = red[0] + red[2];
    s2 = red[1] + red[3];
    float mu = s1 * (1.f / HID);
    float var = s2 * (1.f / HID) - mu * mu;
    float rstd = rsqrtf(var + 1e-5f);
    float y = fmaf(gamma_l[c] * (v - mu), rstd, beta_l[c]);
    y = elu_f(y);
    if (has_res) y += (float)xlr[(size_t)n * NCAT + 1024 + c];
    if (do_pool) atomicAdd(&hsum[(size_t)batch[n] * HID + c], y);
    else hbf_out[(size_t)n * HID + c] = (bf16)y;
}

// ---------------- MLP head ----------------
__global__ __launch_bounds__(128) void k_mlp(const float* __restrict__ hsum,
                                             const int* __restrict__ cnt,
                                             const float* __restrict__ W1, const float* __restrict__ b1,
                                             const float* __restrict__ W2, const float* __restrict__ b2,
                                             const float* __restrict__ W3, const float* __restrict__ b3,
                                             float* __restrict__ out) {
    int g = blockIdx.x, t = threadIdx.x;
    __shared__ float hg[HID], z1[HID], z2[64];
    float invc = 1.f / fmaxf((float)cnt[g], 1.f);
    hg[t] = hsum[(size_t)g * HID + t] * invc;
    __syncthreads();
    float s = b1[t];
#pragma unroll 8
    for (int k = 0; k < HID; k++) s = fmaf(hg[k], W1[k * HID + t], s);
    z1[t] = fmaxf(s, 0.f);
    __syncthreads();
    if (t < 64) {
        float s2 = b2[t];
#pragma unroll 8
        for (int k = 0; k < HID; k++) s2 = fmaf(z1[k], W2[k * 64 + t], s2);
        z2[t] = fmaxf(s2, 0.f);
    }
    __syncthreads();
    if (t < 64) {
        float s3 = z2[t] * W3[t];
#pragma unroll
        for (int off = 1; off < 64; off <<= 1) s3 += __shfl_xor(s3, off, 64);
        if (t == 0) out[g] = s3 + b3[0];
    }
}

// ---------------- host launcher ----------------
extern "C" void kernel_launch(void* const* d_in, const int* in_sizes, int n_in,
                              void* d_out, int out_size, void* d_ws, size_t ws_size,
                              hipStream_t stream) {
    const float* x         = (const float*)d_in[0];
    const int*   ei        = (const int*)  d_in[1];
    const float* edge_attr = (const float*)d_in[2];
    const int*   batch     = (const int*)  d_in[3];
    const float* Win       = (const float*)d_in[4];
    const float* b_in      = (const float*)d_in[5];
    const float* Wl        = (const float*)d_in[6];
    const float* bl        = (const float*)d_in[7];
    const float* Wr        = (const float*)d_in[8];
    const float* br        = (const float*)d_in[9];
    const float* We        = (const float*)d_in[10];
    const float* att       = (const float*)d_in[11];
    const float* b_gat     = (const float*)d_in[12];
    const float* gamma     = (const float*)d_in[13];
    const float* beta      = (const float*)d_in[14];
    const float* Wres      = (const float*)d_in[15];
    const float* bres      = (const float*)d_in[16];
    const float* W1        = (const float*)d_in[17];
    const float* b1        = (const float*)d_in[18];
    const float* W2        = (const float*)d_in[19];
    const float* b2        = (const float*)d_in[20];
    const float* W3        = (const float*)d_in[21];
    const float* b3        = (const float*)d_in[22];
    float* out = (float*)d_out;

    char* ws = (char*)d_ws;
    size_t off = 0;
    auto alloc = [&](size_t bytes) -> void* {
        void* p = ws + off;
        off = (off + bytes + 255) & ~(size_t)255;
        return p;
    };
    bf16*  h_bf    = (bf16*) alloc((size_t)N_NODES * HID * 2);
    bf16*  xlr     = (bf16*) alloc((size_t)N_NODES * NCAT * 2);
    bf16*  WT      = (bf16*) alloc((size_t)LAYERS * NCAT * HID * 2);
    float* bcat    = (float*)alloc((size_t)LAYERS * NCAT * 4);
    float* slogit  = (float*)alloc((size_t)N_EDGES * 4 * 4);
    float* ea_s    = (float*)alloc((size_t)N_EDGES * EDGE_DIM * 4);
    // contiguous zero region: [hsum | cnt | deg]
    char*  zbase   = ws + off;
    float* hsum    = (float*)alloc((size_t)NUM_GRAPHS * HID * 4);
    int*   cnt     = (int*)  alloc((size_t)NUM_GRAPHS * 4);
    int*   deg     = (int*)  alloc((size_t)N_NODES * 4);
    size_t zlen    = (size_t)((ws + off) - zbase);
    int*   rowst   = (int*)  alloc((size_t)(N_NODES + 1) * 4);
    int*   cursor  = (int*)  alloc((size_t)N_NODES * 4);
    int*   ssrc    = (int*)  alloc((size_t)N_EDGES * 4);
    int*   sdst    = (int*)  alloc((size_t)N_EDGES * 4);
    (void)ws_size; // requires ~37 MB

    hipMemsetAsync(zbase, 0, zlen, stream);

    k_prep_w<<<dim3(9, LAYERS, 8), 128, 0, stream>>>(Wl, bl, Wr, br, Wres, bres, WT, bcat);
    k_degree<<<(N_EDGES + 255) / 256, 256, 0, stream>>>(ei, batch, deg, cnt);
    k_scan<<<1, 1024, 0, stream>>>(deg, rowst, cursor);
    k_scatter<<<(N_EDGES + 255) / 256, 256, 0, stream>>>(ei, edge_attr, cursor, ssrc, sdst, ea_s);
    k_init_h<<<N_NODES, 128, 0, stream>>>(x, Win, b_in, h_bf);

    const int MG = (N_NODES + 127) / 128;  // 79
    for (int i = 0; i < LAYERS; i++) {
        int ntiles = (i > 0) ? (NCAT / 128) : (1024 / 128);
        k_gemm_mfma<<<dim3(MG, ntiles), 256, 0, stream>>>(
            h_bf, WT + (size_t)i * NCAT * HID, bcat + (size_t)i * NCAT, xlr, N_NODES);
        k_edge_logits<<<N_EDGES / EPB, 256, 0, stream>>>(
            xlr, ea_s, ssrc, sdst,
            We + (size_t)i * EDGE_DIM * HC, att + (size_t)i * HEADS * HID, slogit);
        k_edge_agg<<<N_NODES, 128, 0, stream>>>(
            xlr, rowst, ssrc, slogit,
            b_gat + (size_t)i * HID, gamma + (size_t)i * HID, beta + (size_t)i * HID,
            (i > 0) ? 1 : 0,
            batch, hsum, (i == LAYERS - 1) ? 1 : 0, h_bf);
    }

    k_mlp<<<NUM_GRAPHS, 128, 0, stream>>>(hsum, cnt, W1, b1, W2, b2, W3, b3, out);
}

// Round 7
// 429.449 us; speedup vs baseline: 9.4426x; 1.4871x over previous
//
#include <hip/hip_runtime.h>

#define N_NODES 10000
#define N_EDGES 100000
#define IN_CH 64
#define EDGE_DIM 16
#define HID 128
#define HEADS 4
#define HC 512          // HEADS*HID
#define LAYERS 4
#define NUM_GRAPHS 256
#define NCAT 1152       // 512(xl) + 512(xr) + 128(res) packed cols
#define LDP 136         // padded LDS stride (bf16 elems)

typedef __bf16 bf16;
typedef __bf16 bf16x8 __attribute__((ext_vector_type(8)));
typedef __bf16 bf16x4 __attribute__((ext_vector_type(4)));
typedef float floatx4 __attribute__((ext_vector_type(4)));
typedef float f32x2 __attribute__((ext_vector_type(2)));

__device__ __forceinline__ float elu_f(float x) { return x > 0.f ? x : (__expf(x) - 1.f); }

// ---------------- weight prep: WT[l][n][k] bf16, coalesced via LDS transpose ----
// grid (9, LAYERS, 8), block 128. nt: 0-3=Wl, 4-7=Wr, 8=Wres. z = 16-row k-chunk.
__global__ __launch_bounds__(128) void k_prep_w(
    const float* __restrict__ Wl, const float* __restrict__ bl,
    const float* __restrict__ Wr, const float* __restrict__ br,
    const float* __restrict__ Wres, const float* __restrict__ bres,
    bf16* __restrict__ WT, float* __restrict__ bcat) {
    __shared__ float tile[16][129];
    int nt = blockIdx.x, i = blockIdx.y, z = blockIdx.z;
    int t = threadIdx.x;
    int n0 = nt * 128;
    const float* base = nullptr; const float* bsrc = nullptr; int ld = 0;
    if (nt < 4)       { base = Wl + (size_t)i * HID * HC + n0;            bsrc = bl + i * HC + n0;              ld = HC; }
    else if (nt < 8)  { base = Wr + (size_t)i * HID * HC + (n0 - 512);    bsrc = br + i * HC + (n0 - 512);      ld = HC; }
    else if (i > 0)   { base = Wres + (size_t)(i - 1) * HID * HID;        bsrc = bres + (size_t)(i - 1) * HID;  ld = HID; }
    if (base) {
#pragma unroll
        for (int r = 0; r < 16; r++) tile[r][t] = base[(size_t)(z * 16 + r) * ld + t];
    } else {
#pragma unroll
        for (int r = 0; r < 16; r++) tile[r][t] = 0.f;
    }
    __syncthreads();
    int n = n0 + t;
    if (z == 0) bcat[(size_t)i * NCAT + n] = base ? bsrc[t] : 0.f;
    bf16* dst = WT + ((size_t)i * NCAT + n) * HID + z * 16;
#pragma unroll
    for (int kc = 0; kc < 2; kc++) {
        bf16x8 v;
#pragma unroll
        for (int u = 0; u < 8; u++) v[u] = (bf16)tile[kc * 8 + u][t];
        *(bf16x8*)(dst + kc * 8) = v;
    }
}

// ---------------- h0 = elu(x @ Win + b_in) ----------------
__global__ __launch_bounds__(128) void k_init_h(const float* __restrict__ x,
                                                const float* __restrict__ Win,
                                                const float* __restrict__ b_in,
                                                bf16* __restrict__ h_bf) {
    __shared__ float xs[IN_CH];
    int n = blockIdx.x, t = threadIdx.x;
    if (t < IN_CH) xs[t] = x[(size_t)n * IN_CH + t];
    __syncthreads();
    float s = b_in[t];
#pragma unroll 8
    for (int k = 0; k < IN_CH; k++) s = fmaf(xs[k], Win[k * HID + t], s);
    h_bf[(size_t)n * HID + t] = (bf16)elu_f(s);
}

// ---------------- MFMA bf16 GEMM: C[M,NCAT] = A[M,128] @ WT^T + bias ------
// operand-swapped mfma(b,a) -> lane holds 4 CONSECUTIVE COLUMNS of one row
// -> epilogue is 16x 8B vector stores instead of 64x 2B scalar stores.
__global__ __launch_bounds__(256, 2) void k_gemm_mfma(
    const bf16* __restrict__ A, const bf16* __restrict__ WT,
    const float* __restrict__ bcat, bf16* __restrict__ C, int M) {
    __shared__ __align__(16) unsigned short As[128 * LDP];
    __shared__ __align__(16) unsigned short Bs[128 * LDP];
    int t = threadIdx.x;
    int r0 = blockIdx.x * 128, c0 = blockIdx.y * 128;
#pragma unroll
    for (int i = 0; i < 8; i++) {
        int idx = t + i * 256;
        int row = idx >> 4;
        int ch = idx & 15;
        int r = r0 + row; if (r >= M) r = M - 1;
        uint4 va = *(const uint4*)(A + (size_t)r * HID + ch * 8);
        *(uint4*)&As[row * LDP + ch * 8] = va;
        uint4 vb = *(const uint4*)(WT + (size_t)(c0 + row) * HID + ch * 8);
        *(uint4*)&Bs[row * LDP + ch * 8] = vb;
    }
    __syncthreads();

    int wave = t >> 6, lane = t & 63;
    int wm = wave & 1, wn = wave >> 1;
    int quad = lane >> 4, lm = lane & 15;
    floatx4 zero = {0.f, 0.f, 0.f, 0.f};
    floatx4 acc[4][4];
#pragma unroll
    for (int mi = 0; mi < 4; mi++)
#pragma unroll
        for (int ni = 0; ni < 4; ni++) acc[mi][ni] = zero;

    const unsigned short* Ab = &As[(wm * 64 + lm) * LDP + quad * 8];
    const unsigned short* Bb = &Bs[(wn * 64 + lm) * LDP + quad * 8];
#pragma unroll
    for (int ks = 0; ks < 4; ks++) {
        bf16x8 af[4], bfr[4];
#pragma unroll
        for (int mi = 0; mi < 4; mi++) af[mi] = *(const bf16x8*)(Ab + mi * 16 * LDP + ks * 32);
#pragma unroll
        for (int ni = 0; ni < 4; ni++) bfr[ni] = *(const bf16x8*)(Bb + ni * 16 * LDP + ks * 32);
#pragma unroll
        for (int mi = 0; mi < 4; mi++)
#pragma unroll
            for (int ni = 0; ni < 4; ni++)
                acc[mi][ni] = __builtin_amdgcn_mfma_f32_16x16x32_bf16(bfr[ni], af[mi], acc[mi][ni], 0, 0, 0);
    }

#pragma unroll
    for (int mi = 0; mi < 4; mi++) {
        int row = r0 + wm * 64 + mi * 16 + lm;
        if (row < M) {
            bf16* crow = C + (size_t)row * NCAT;
#pragma unroll
            for (int ni = 0; ni < 4; ni++) {
                int cb = c0 + wn * 64 + ni * 16 + quad * 4;
                float4 b4 = *(const float4*)(bcat + cb);
                floatx4 v = acc[mi][ni];
                bf16x4 o = {(bf16)(v[0] + b4.x), (bf16)(v[1] + b4.y),
                            (bf16)(v[2] + b4.z), (bf16)(v[3] + b4.w)};
                *(bf16x4*)(crow + cb) = o;
            }
        }
    }
}

// ---------------- CSR build (+ per-graph node counts folded in) ----------------
__global__ void k_degree(const int* __restrict__ ei, const int* __restrict__ batch,
                         int* __restrict__ deg, int* __restrict__ cnt) {
    int e = blockIdx.x * blockDim.x + threadIdx.x;
    if (e < N_EDGES) atomicAdd(&deg[ei[N_EDGES + e]], 1);
    if (e < N_NODES) atomicAdd(&cnt[batch[e]], 1);
}

// shfl-based scan
__global__ __launch_bounds__(1024) void k_scan(const int* __restrict__ deg,
                                               int* __restrict__ row_start,
                                               int* __restrict__ cursor) {
    __shared__ int wsum[16];
    __shared__ int carry_s;
    int t = threadIdx.x;
    int wave = t >> 6, lane = t & 63;
    if (t == 0) { carry_s = 0; row_start[0] = 0; }
    __syncthreads();
    for (int base = 0; base < N_NODES; base += 1024) {
        int i = base + t;
        int v = (i < N_NODES) ? deg[i] : 0;
        int incl = v;
#pragma unroll
        for (int off = 1; off < 64; off <<= 1) {
            int u = __shfl_up(incl, off, 64);
            if (lane >= off) incl += u;
        }
        if (lane == 63) wsum[wave] = incl;
        __syncthreads();
        if (wave == 0) {
            int ws = (lane < 16) ? wsum[lane] : 0;
#pragma unroll
            for (int off = 1; off < 16; off <<= 1) {
                int u = __shfl_up(ws, off, 64);
                if (lane >= off) ws += u;
            }
            if (lane < 16) wsum[lane] = ws;
        }
        __syncthreads();
        int carry = carry_s;
        int chunk_total = wsum[15];
        int total = carry + ((wave == 0) ? 0 : wsum[wave - 1]) + incl;
        if (i < N_NODES) { row_start[i + 1] = total; cursor[i] = total - v; }
        __syncthreads();
        if (t == 0) carry_s = carry + chunk_total;
    }
}

// scatter edges into CSR order; also permute edge_attr so fused reads are coalesced
__global__ void k_scatter(const int* __restrict__ ei, const float* __restrict__ edge_attr,
                          int* __restrict__ cursor,
                          int* __restrict__ ssrc, float* __restrict__ ea_s) {
    int e = blockIdx.x * blockDim.x + threadIdx.x;
    if (e < N_EDGES) {
        int d = ei[N_EDGES + e];
        int pos = atomicAdd(&cursor[d], 1);
        ssrc[pos] = ei[e];
        const float4* s4 = (const float4*)(edge_attr + (size_t)e * EDGE_DIM);
        float4* d4 = (float4*)(ea_s + (size_t)pos * EDGE_DIM);
        d4[0] = s4[0]; d4[1] = s4[1]; d4[2] = s4[2]; d4[3] = s4[3];
    }
}

// ---------------- fused edge phase: logits + softmax + aggregate + LN --------
// one block (128 thr = 2 waves) per destination node. No max pass (softmax is
// shift-invariant, logits O(+-20), fp32 exp safe — validated R4-R6). Edge
// iterations fully independent -> unroll-2 with split accumulators. xl gathered
// ONCE, used for both logit and aggregation. f32x2 packed FMA for ea@We.
__device__ __forceinline__ void edge_body(
    int j, const int* __restrict__ ssrc, const float* __restrict__ ea_s,
    const bf16* __restrict__ xlr, int c0, const float* __restrict__ We_l,
    float xr0, float xr1, float xr2, float xr3, float4 att4,
    float& lsum, float4& acc) {
    int s = ssrc[j];
    const float4* eap = (const float4*)(ea_s + (size_t)j * EDGE_DIM);
    float4 q0 = eap[0], q1 = eap[1], q2 = eap[2], q3 = eap[3];
    float ea[16] = {q0.x, q0.y, q0.z, q0.w, q1.x, q1.y, q1.z, q1.w,
                    q2.x, q2.y, q2.z, q2.w, q3.x, q3.y, q3.z, q3.w};
    bf16x4 vl = *(const bf16x4*)(xlr + (size_t)s * NCAT + c0);
    float xl0 = (float)vl[0], xl1 = (float)vl[1], xl2 = (float)vl[2], xl3 = (float)vl[3];
    f32x2 e01 = {0.f, 0.f}, e23 = {0.f, 0.f};
#pragma unroll
    for (int k = 0; k < 16; k++) {
        float4 w = *(const float4*)(We_l + k * HC + c0);
        f32x2 w01 = {w.x, w.y}, w23 = {w.z, w.w};
        e01 += ea[k] * w01;
        e23 += ea[k] * w23;
    }
    float m0 = xl0 + xr0 + e01.x; m0 = fmaxf(m0, 0.2f * m0);
    float m1 = xl1 + xr1 + e01.y; m1 = fmaxf(m1, 0.2f * m1);
    float m2 = xl2 + xr2 + e23.x; m2 = fmaxf(m2, 0.2f * m2);
    float m3 = xl3 + xr3 + e23.y; m3 = fmaxf(m3, 0.2f * m3);
    float partial = m0 * att4.x + m1 * att4.y + m2 * att4.z + m3 * att4.w;
#pragma unroll
    for (int off = 1; off < 32; off <<= 1) partial += __shfl_xor(partial, off, 64);
    float p = __expf(partial);
    lsum += p;
    acc.x = fmaf(p, xl0, acc.x);
    acc.y = fmaf(p, xl1, acc.y);
    acc.z = fmaf(p, xl2, acc.z);
    acc.w = fmaf(p, xl3, acc.w);
}

__global__ __launch_bounds__(128) void k_edge_fused(
    const bf16* __restrict__ xlr, const float* __restrict__ ea_s,
    const int* __restrict__ row_start, const int* __restrict__ ssrc,
    const float* __restrict__ We_l, const float* __restrict__ att_l,
    const float* __restrict__ bgat_l, const float* __restrict__ gamma_l,
    const float* __restrict__ beta_l,
    int has_res,
    const int* __restrict__ batch, float* __restrict__ hsum, int do_pool,
    bf16* __restrict__ hbf_out) {
    int n = blockIdx.x;
    int t = threadIdx.x;
    int wave = t >> 6;
    int lane = t & 63;
    int c0 = wave * 256 + lane * 4;
    int head = c0 >> 7;

    float4 att4 = *(const float4*)(att_l + head * HID + (c0 & 127));
    bf16x4 vr = *(const bf16x4*)(xlr + (size_t)n * NCAT + 512 + c0);
    float xr0 = (float)vr[0], xr1 = (float)vr[1], xr2 = (float)vr[2], xr3 = (float)vr[3];

    int e0 = row_start[n], e1 = row_start[n + 1];
    float l0 = 0.f, l1 = 0.f;
    float4 a0 = {0.f, 0.f, 0.f, 0.f}, a1 = {0.f, 0.f, 0.f, 0.f};
    int j = e0;
    for (; j + 1 < e1; j += 2) {
        edge_body(j,     ssrc, ea_s, xlr, c0, We_l, xr0, xr1, xr2, xr3, att4, l0, a0);
        edge_body(j + 1, ssrc, ea_s, xlr, c0, We_l, xr0, xr1, xr2, xr3, att4, l1, a1);
    }
    if (j < e1)
        edge_body(j,     ssrc, ea_s, xlr, c0, We_l, xr0, xr1, xr2, xr3, att4, l0, a0);

    float inv = 1.f / (l0 + l1 + 1e-16f);

    __shared__ float sout[HC];
    __shared__ float red[4];
    sout[c0 + 0] = (a0.x + a1.x) * inv;
    sout[c0 + 1] = (a0.y + a1.y) * inv;
    sout[c0 + 2] = (a0.z + a1.z) * inv;
    sout[c0 + 3] = (a0.w + a1.w) * inv;
    __syncthreads();

    int c = t;
    float v = 0.25f * (sout[c] + sout[c + 128] + sout[c + 256] + sout[c + 384]) + bgat_l[c];
    float s1 = v, s2 = v * v;
#pragma unroll
    for (int off = 1; off < 64; off <<= 1) {
        s1 += __shfl_xor(s1, off, 64);
        s2 += __shfl_xor(s2, off, 64);
    }
    if (lane == 0) { red[wave * 2] = s1; red[wave * 2 + 1] = s2; }
    __syncthreads();
    s1 = red[0] + red[2];
    s2 = red[1] + red[3];
    float mu = s1 * (1.f / HID);
    float var = s2 * (1.f / HID) - mu * mu;
    float rstd = rsqrtf(var + 1e-5f);
    float y = fmaf(gamma_l[c] * (v - mu), rstd, beta_l[c]);
    y = elu_f(y);
    if (has_res) y += (float)xlr[(size_t)n * NCAT + 1024 + c];
    if (do_pool) atomicAdd(&hsum[(size_t)batch[n] * HID + c], y);
    else hbf_out[(size_t)n * HID + c] = (bf16)y;
}

// ---------------- MLP head ----------------
__global__ __launch_bounds__(128) void k_mlp(const float* __restrict__ hsum,
                                             const int* __restrict__ cnt,
                                             const float* __restrict__ W1, const float* __restrict__ b1,
                                             const float* __restrict__ W2, const float* __restrict__ b2,
                                             const float* __restrict__ W3, const float* __restrict__ b3,
                                             float* __restrict__ out) {
    int g = blockIdx.x, t = threadIdx.x;
    __shared__ float hg[HID], z1[HID], z2[64];
    float invc = 1.f / fmaxf((float)cnt[g], 1.f);
    hg[t] = hsum[(size_t)g * HID + t] * invc;
    __syncthreads();
    float s = b1[t];
#pragma unroll 8
    for (int k = 0; k < HID; k++) s = fmaf(hg[k], W1[k * HID + t], s);
    z1[t] = fmaxf(s, 0.f);
    __syncthreads();
    if (t < 64) {
        float s2 = b2[t];
#pragma unroll 8
        for (int k = 0; k < HID; k++) s2 = fmaf(z1[k], W2[k * 64 + t], s2);
        z2[t] = fmaxf(s2, 0.f);
    }
    __syncthreads();
    if (t < 64) {
        float s3 = z2[t] * W3[t];
#pragma unroll
        for (int off = 1; off < 64; off <<= 1) s3 += __shfl_xor(s3, off, 64);
        if (t == 0) out[g] = s3 + b3[0];
    }
}

// ---------------- host launcher ----------------
extern "C" void kernel_launch(void* const* d_in, const int* in_sizes, int n_in,
                              void* d_out, int out_size, void* d_ws, size_t ws_size,
                              hipStream_t stream) {
    const float* x         = (const float*)d_in[0];
    const int*   ei        = (const int*)  d_in[1];
    const float* edge_attr = (const float*)d_in[2];
    const int*   batch     = (const int*)  d_in[3];
    const float* Win       = (const float*)d_in[4];
    const float* b_in      = (const float*)d_in[5];
    const float* Wl        = (const float*)d_in[6];
    const float* bl        = (const float*)d_in[7];
    const float* Wr        = (const float*)d_in[8];
    const float* br        = (const float*)d_in[9];
    const float* We        = (const float*)d_in[10];
    const float* att       = (const float*)d_in[11];
    const float* b_gat     = (const float*)d_in[12];
    const float* gamma     = (const float*)d_in[13];
    const float* beta      = (const float*)d_in[14];
    const float* Wres      = (const float*)d_in[15];
    const float* bres      = (const float*)d_in[16];
    const float* W1        = (const float*)d_in[17];
    const float* b1        = (const float*)d_in[18];
    const float* W2        = (const float*)d_in[19];
    const float* b2        = (const float*)d_in[20];
    const float* W3        = (const float*)d_in[21];
    const float* b3        = (const float*)d_in[22];
    float* out = (float*)d_out;

    char* ws = (char*)d_ws;
    size_t off = 0;
    auto alloc = [&](size_t bytes) -> void* {
        void* p = ws + off;
        off = (off + bytes + 255) & ~(size_t)255;
        return p;
    };
    bf16*  h_bf    = (bf16*) alloc((size_t)N_NODES * HID * 2);
    bf16*  xlr     = (bf16*) alloc((size_t)N_NODES * NCAT * 2);
    bf16*  WT      = (bf16*) alloc((size_t)LAYERS * NCAT * HID * 2);
    float* bcat    = (float*)alloc((size_t)LAYERS * NCAT * 4);
    float* ea_s    = (float*)alloc((size_t)N_EDGES * EDGE_DIM * 4);
    // contiguous zero region: [hsum | cnt | deg]
    char*  zbase   = ws + off;
    float* hsum    = (float*)alloc((size_t)NUM_GRAPHS * HID * 4);
    int*   cnt     = (int*)  alloc((size_t)NUM_GRAPHS * 4);
    int*   deg     = (int*)  alloc((size_t)N_NODES * 4);
    size_t zlen    = (size_t)((ws + off) - zbase);
    int*   rowst   = (int*)  alloc((size_t)(N_NODES + 1) * 4);
    int*   cursor  = (int*)  alloc((size_t)N_NODES * 4);
    int*   ssrc    = (int*)  alloc((size_t)N_EDGES * 4);
    (void)ws_size; // requires ~36 MB

    hipMemsetAsync(zbase, 0, zlen, stream);

    k_prep_w<<<dim3(9, LAYERS, 8), 128, 0, stream>>>(Wl, bl, Wr, br, Wres, bres, WT, bcat);
    k_degree<<<(N_EDGES + 255) / 256, 256, 0, stream>>>(ei, batch, deg, cnt);
    k_scan<<<1, 1024, 0, stream>>>(deg, rowst, cursor);
    k_scatter<<<(N_EDGES + 255) / 256, 256, 0, stream>>>(ei, edge_attr, cursor, ssrc, ea_s);
    k_init_h<<<N_NODES, 128, 0, stream>>>(x, Win, b_in, h_bf);

    const int MG = (N_NODES + 127) / 128;  // 79
    for (int i = 0; i < LAYERS; i++) {
        int ntiles = (i > 0) ? (NCAT / 128) : (1024 / 128);
        k_gemm_mfma<<<dim3(MG, ntiles), 256, 0, stream>>>(
            h_bf, WT + (size_t)i * NCAT * HID, bcat + (size_t)i * NCAT, xlr, N_NODES);
        k_edge_fused<<<N_NODES, 128, 0, stream>>>(
            xlr, ea_s, rowst, ssrc,
            We + (size_t)i * EDGE_DIM * HC, att + (size_t)i * HEADS * HID,
            b_gat + (size_t)i * HID, gamma + (size_t)i * HID, beta + (size_t)i * HID,
            (i > 0) ? 1 : 0,
            batch, hsum, (i == LAYERS - 1) ? 1 : 0, h_bf);
    }

    k_mlp<<<NUM_GRAPHS, 128, 0, stream>>>(hsum, cnt, W1, b1, W2, b2, W3, b3, out);
}